// Round 13
// baseline (201.733 us; speedup 1.0000x reference)
//
#include <hip/hip_runtime.h>

typedef unsigned short u16;
typedef unsigned u32;
typedef float f32x4 __attribute__((ext_vector_type(4)));
typedef __bf16 bf16x8 __attribute__((ext_vector_type(8)));
typedef __bf16 bf16x2 __attribute__((ext_vector_type(2)));
typedef u32 u32x4 __attribute__((ext_vector_type(4)));
typedef u16 u16x4 __attribute__((ext_vector_type(4)));
typedef int i32x2 __attribute__((ext_vector_type(2)));

#define MFMA_16x16x32(a, b, c) __builtin_amdgcn_mfma_f32_16x16x32_bf16((a), (b), (c), 0, 0, 0)

#if __has_builtin(__builtin_amdgcn_exp2f)
#define EXP2(x) __builtin_amdgcn_exp2f(x)
#else
#define EXP2(x) exp2f(x)
#endif

// ---------- helpers ----------

__device__ __forceinline__ u16 f2bf(float f) {
  unsigned u = __builtin_bit_cast(unsigned, f);
  unsigned r = ((u >> 16) & 1u) + 0x7FFFu;  // round-to-nearest-even
  return (u16)((u + r) >> 16);
}

__device__ __forceinline__ u32 pk2(float x, float y) {  // lo=x, hi=y as bf16
  bf16x2 v = {(__bf16)x, (__bf16)y};
  return __builtin_bit_cast(u32, v);
}

// async global->LDS, 16B per lane. LDS dest must be wave-uniform base + lane*16.
__device__ __forceinline__ void gload16(const void* g, void* l) {
  __builtin_amdgcn_global_load_lds(
      (const __attribute__((address_space(1))) void*)g,
      (__attribute__((address_space(3))) void*)l, 16, 0, 0);
}

// ===== GEMM operand tiling (K=1024, consumed as 128-row x 32-k tiles) =====
// frag f (0..7) of tile (R,kb): rows (f>>2)*64+(f&3)*16+(l&15), k (l>>4)*8+e.
// u16 offset(row,k) = ((R*32+kb)*8 + f)*512 + ((k>>3)&3)*128 + (row&15)*8 + (k&7)
//   R=row>>7, rr=row&127, f=(rr>>6)*4+((rr>>4)&3), kb=k>>5.
// Readers then stage with gload16 at (frag base + lane*16) -- fully coalesced.

// ---------- conversion kernels ----------

// x [8192][1024] fp32 -> xb tiled bf16. One thread = one 8-elem slot.
__global__ void cvt_to_bf16(const float* __restrict__ in, u16* __restrict__ out, int n) {
  const int s = blockIdx.x * 256 + threadIdx.x;  // slot index
  if (s * 8 >= n) return;
  const int l = s & 63, f = (s >> 6) & 7, kb = (s >> 9) & 31, R = s >> 14;
  const int rr = ((f >> 2) << 6) + ((f & 3) << 4) + (l & 15);
  const int row = (R << 7) + rr;
  const int k = (kb << 5) + ((l >> 4) << 3);
  const float* src = in + (size_t)row * 1024 + k;
  const f32x4 a = *(const f32x4*)src;
  const f32x4 b = *(const f32x4*)(src + 4);
  u16x4 u0, u1;
#pragma unroll
  for (int j = 0; j < 4; ++j) { u0[j] = f2bf(a[j]); u1[j] = f2bf(b[j]); }
  *(u16x4*)(out + (size_t)s * 8) = u0;
  *(u16x4*)(out + (size_t)s * 8 + 4) = u1;
}

// w [rows=K][cols=N] fp32 -> tiled-by-N bf16 (out(n,k) = w[k][n]).
__global__ void transpose_cvt(const float* __restrict__ in, u16* __restrict__ out,
                              int rows, int cols) {
  __shared__ float t[64][65];
  const int rb = blockIdx.y * 64, cb = blockIdx.x * 64;  // rb: k-base, cb: n-base
  for (int i = threadIdx.x; i < 4096; i += 256) {
    const int r = i >> 6, c = i & 63;
    t[r][c] = in[(size_t)(rb + r) * cols + cb + c];
  }
  __syncthreads();
  for (int u = threadIdx.x; u < 512; u += 256) {
    const int c = u >> 3, k8 = u & 7;
    const int nrow = cb + c;
    const int kg = rb + k8 * 8;
    const int R = nrow >> 7, rr = nrow & 127;
    const int fB = ((rr >> 6) << 2) + ((rr >> 4) & 3);
    const int kb = kg >> 5, koct = (kg >> 3) & 3;
    u16* dst = out + (((size_t)R * 32 + kb) * 8 + fB) * 512 + ((koct << 4) + (rr & 15)) * 8;
    u16x4 u0, u1;
#pragma unroll
    for (int j = 0; j < 4; ++j) {
      u0[j] = f2bf(t[k8 * 8 + j][c]);
      u1[j] = f2bf(t[k8 * 8 + 4 + j][c]);
    }
    *(u16x4*)dst = u0;
    *(u16x4*)(dst + 4) = u1;
  }
}

// ---------- GEMM: C = A * Bt^T + bias (A, Bt both DRAM-fragment-tiled) ----------
// 128x128 tile, BK=32, 2-phase static double-buffer (32 KB LDS), identity frag
// slots (conflict-free b128, zero per-iter addr VALU), coalesced 1KB gloads,
// XCD-swizzled block id.
// EPI=0: scatter to flash-tiled q/k/v buffers (bf16, +bias; V sigma-permuted)
// EPI=1: fp32 out[M][N] + bias (row-major)
template <int EPI>
__global__ __launch_bounds__(256, 4) void gemm_bt(
    const u16* __restrict__ A, const u16* __restrict__ Bt, int K,
    const float* __restrict__ bias,
    u16* __restrict__ oq, u16* __restrict__ ok, u16* __restrict__ ov,
    float* __restrict__ of, int N, int nbx) {
  __shared__ __align__(16) u16 As[2][4096];
  __shared__ __align__(16) u16 Bs[2][4096];
  const int tid = threadIdx.x;
  const int lane = tid & 63, w = tid >> 6;
  const int g = lane >> 4, cc = lane & 15;
  const int wr = w >> 1, wc = w & 1;

  // XCD-aware swizzle (grid is a multiple of 8 -> bijective)
  const int cpx = gridDim.x >> 3;
  const int bid = ((int)blockIdx.x & 7) * cpx + ((int)blockIdx.x >> 3);
  const int bx = bid % nbx, by = bid / nbx;

  // tiled sources: frag stride 512, 32-k tile stride 4096 (u16)
  const u16* pa = A + ((size_t)by * 256 + w) * 512 + lane * 8;
  const u16* pb = Bt + ((size_t)bx * 256 + w) * 512 + lane * 8;

  f32x4 acc[4][4] = {};

#define STG(S, T)                                              \
  do {                                                         \
    const size_t o_ = (size_t)(T) * 4096;                      \
    gload16(pa + o_, &As[S][w * 512 + lane * 8]);              \
    gload16(pa + o_ + 2048, &As[S][(w + 4) * 512 + lane * 8]); \
    gload16(pb + o_, &Bs[S][w * 512 + lane * 8]);              \
    gload16(pb + o_ + 2048, &Bs[S][(w + 4) * 512 + lane * 8]); \
  } while (0)

#define CMP(S, DOSTG, T)                                                 \
  do {                                                                   \
    bf16x8 af[4], bf[4];                                                 \
    _Pragma("unroll") for (int mi = 0; mi < 4; ++mi)                     \
        af[mi] = *(const bf16x8*)&As[S][(wr * 4 + mi) * 512 + lane * 8]; \
    _Pragma("unroll") for (int ni = 0; ni < 4; ++ni)                     \
        bf[ni] = *(const bf16x8*)&Bs[S][(wc * 4 + ni) * 512 + lane * 8]; \
    if (DOSTG) STG(S ^ 1, T);                                            \
    __builtin_amdgcn_s_setprio(1);                                       \
    _Pragma("unroll") for (int mi = 0; mi < 4; ++mi)                     \
      _Pragma("unroll") for (int ni = 0; ni < 4; ++ni)                   \
          acc[mi][ni] = MFMA_16x16x32(af[mi], bf[ni], acc[mi][ni]);      \
    __builtin_amdgcn_s_setprio(0);                                       \
  } while (0)

  STG(0, 0);
  __syncthreads();

  const int np = (K >> 5) >> 1;  // pairs of 32-k tiles (16 for K=1024)
  for (int p = 0; p < np - 1; ++p) {
    CMP(0, true, 2 * p + 1);
    __syncthreads();
    CMP(1, true, 2 * p + 2);
    __syncthreads();
  }
  CMP(0, true, 2 * np - 1);
  __syncthreads();
  CMP(1, false, 0);

#undef STG
#undef CMP

  // epilogue: D layout col=lane&15, row=(lane>>4)*4+r
  const int m00 = by * 128 + wr * 64 + 4 * g;
  const int n00 = bx * 128 + wc * 64;
#pragma unroll
  for (int ni = 0; ni < 4; ++ni) {
    const int n = n00 + ni * 16 + cc;
    const float bn = bias[n];
    if constexpr (EPI == 0) {
      const int which = n >> 10;  // 0=q 1=k 2=v (wave-uniform)
      const int d = n & 1023;
      const int h = d >> 6, dh = d & 63;
      const int dcf = dh >> 5, gf = (dh >> 3) & 3, e = dh & 7;  // q/k frag coords
      const int niv = dh >> 4, ccv = dh & 15;                   // v frag coords
#pragma unroll
      for (int mi = 0; mi < 4; ++mi) {
        const int mb = m00 + mi * 16;
        const int b = mb >> 11, t0b = mb & 2047;
        const int bh2 = b * 16 + h;
        const int kt = t0b >> 7, tr = t0b & 127;  // tr%4==0; r adds to low bits
        if (which == 2) {
          const int kk0 = (tr & ~12) | ((tr & 4) << 1) | ((tr & 8) >> 1);
          const int ko = kk0 >> 5, gv = (kk0 >> 3) & 3, ev = kk0 & 7;  // ev%4==0
          u16x4 pk;
#pragma unroll
          for (int r = 0; r < 4; ++r) pk[r] = f2bf(acc[mi][ni][r] + bn);
          *(u16x4*)&ov[(((size_t)bh2 * 16 + kt) * 16 + ko * 4 + niv) * 512 +
                       ((gv << 4) + ccv) * 8 + ev] = pk;
        } else if (which == 1) {
          const int ki = tr >> 4;
          u16* dst = ok + (((size_t)bh2 * 16 + kt) * 16 + dcf * 8 + ki) * 512 +
                     ((gf << 4) + (tr & 15)) * 8 + e;
#pragma unroll
          for (int r = 0; r < 4; ++r) dst[r * 8] = f2bf(acc[mi][ni][r] + bn);
        } else {
          const int wf = tr >> 5, mif = (tr >> 4) & 1;
          u16* dst = oq + (((size_t)bh2 * 16 + kt) * 16 + wf * 4 + mif * 2 + dcf) * 512 +
                     ((gf << 4) + (tr & 15)) * 8 + e;
#pragma unroll
          for (int r = 0; r < 4; ++r) dst[r * 8] = f2bf(acc[mi][ni][r] + bn);
        }
      }
    } else {
#pragma unroll
      for (int mi = 0; mi < 4; ++mi) {
        const int m = m00 + mi * 16;
#pragma unroll
        for (int r = 0; r < 4; ++r) of[(size_t)(m + r) * N + n] = acc[mi][ni][r] + bn;
      }
    }
  }
}

// ---------- causal flash attention ----------
// Swapped QK^T; stats 2 scalars/lane; PV A-frag via 2x permlane32_swap (sigma
// baked into V). R10 compute body. Staging skeleton = counted-vmcnt pipeline:
// V double-buffered (gload16 direct, issued a full tile ahead), K reg-staged
// into single Ks. Barriers are RAW s_barrier with explicit
// `s_waitcnt vmcnt(4) lgkmcnt(0)` -- never vmcnt(0) in steady state, so K/V
// loads stay in flight across barriers and their latency hides under compute
// (R10's __syncthreads drained vmcnt(0) and exposed it). LDS 48 KB -> still
// 3 blocks/CU; VGPR drops (no V reg staging).
__global__ __launch_bounds__(256, 3) void flash_attn(
    const u16* __restrict__ Qb, const u16* __restrict__ Kb,
    const u16* __restrict__ Vt, u16* __restrict__ Ob) {
  __shared__ __align__(16) u16 Ks[8192];     // 16 frags x 64 lanes x 8
  __shared__ __align__(16) u16 Vs[2][8192];  // double-buffered

  const int bid = blockIdx.x;
  // per-CU load balance: blocks c,c+256,c+512,c+768 share a CU; qt quadruples sum to 30.
  const int tq4 = bid >> 6, t0 = tq4 & 3, ti = tq4 >> 2;
  const int qt = (ti == 0) ? 15 - t0 : (ti == 1) ? 8 + t0 : (ti == 2) ? 7 - t0 : t0;
  const int bh = bid & 63;
  const int tid = threadIdx.x;
  const int lane = tid & 63, w = tid >> 6;
  const int g = lane >> 4, cc = lane & 15;
  const int q0 = qt * 128 + w * 32;

  // Q tiled [bh][qt:16][frag:16][512], frag = w*4+mi*2+dc
  bf16x8 bq[2][2];
  {
    const u16* qp = Qb + (((size_t)bh * 16 + qt) * 16 + w * 4) * 512 + lane * 8;
#pragma unroll
    for (int mi = 0; mi < 2; ++mi)
#pragma unroll
      for (int dc = 0; dc < 2; ++dc)
        bq[mi][dc] = *(const bf16x8*)(qp + (mi * 2 + dc) * 512);
  }

  const char* kp = (const char*)Kb + (size_t)bh * 262144 + w * 1024 + lane * 16;
  const char* vp = (const char*)Vt + (size_t)bh * 262144 + w * 1024 + lane * 16;

  const u32x4 ones_u = {0x3F803F80u, 0x3F803F80u, 0x3F803F80u, 0x3F803F80u};
  const bf16x8 ones = __builtin_bit_cast(bf16x8, ones_u);

  f32x4 acc[2][4] = {};
  f32x4 lsum[2] = {};               // D-layout: lsum[mi][r] = l for q-row 4g+r
  float m_run[2] = {-1e30f, -1e30f};
  const float sc = 0.18033688011112042f;  // (1/8) * log2(e)

  // prologue: K(0)->regs->Ks, V(0)->Vs[0] via gload16, K(1)->regs
  u32x4 kreg[4];
#pragma unroll
  for (int i = 0; i < 4; ++i) kreg[i] = *(const u32x4*)(kp + i * 4096);
  kp += 16384;
#pragma unroll
  for (int i = 0; i < 4; ++i)
    gload16(vp + i * 4096, &Vs[0][(i * 4 + w) * 512 + lane * 8]);
  vp += 16384;
#pragma unroll
  for (int i = 0; i < 4; ++i)
    *(u32x4*)&Ks[(i * 4 + w) * 512 + lane * 8] = kreg[i];
  if (qt > 0) {
#pragma unroll
    for (int i = 0; i < 4; ++i) kreg[i] = *(const u32x4*)(kp + i * 4096);
    kp += 16384;
  }
  __syncthreads();  // one-time full drain: V(0) landed, K(0) visible

#define SMPV(S, MR, LS, AC, B)                                                \
  do {                                                                        \
    float t4[8];                                                              \
    _Pragma("unroll") for (int ki = 0; ki < 8; ++ki)                          \
        t4[ki] = fmaxf(fmaxf(S[ki][0], S[ki][1]), fmaxf(S[ki][2], S[ki][3])); \
    float mx = fmaxf(fmaxf(fmaxf(t4[0], t4[1]), fmaxf(t4[2], t4[3])),         \
                     fmaxf(fmaxf(t4[4], t4[5]), fmaxf(t4[6], t4[7])));        \
    mx = fmaxf(mx, __shfl_xor(mx, 16));                                       \
    mx = fmaxf(mx, __shfl_xor(mx, 32));                                       \
    const float pm = mx * sc;                                                 \
    if (!__all(pm - MR <= 8.f)) {                                             \
      const float mn = fmaxf(MR, pm);                                         \
      const float sf = EXP2(MR - mn);                                         \
      MR = mn;                                                                \
      float sfr[4];                                                           \
      _Pragma("unroll") for (int r = 0; r < 4; ++r)                           \
          sfr[r] = __shfl(sf, (lane & 48) + 4 * g + r);                       \
      _Pragma("unroll") for (int r = 0; r < 4; ++r) LS[r] *= sfr[r];          \
      _Pragma("unroll") for (int ni = 0; ni < 4; ++ni)                        \
        _Pragma("unroll") for (int r = 0; r < 4; ++r) AC[ni][r] *= sfr[r];    \
    }                                                                         \
    const float mcur = MR;                                                    \
    _Pragma("unroll") for (int ko = 0; ko < 4; ++ko) {                        \
      f32x4 pe, po;                                                           \
      _Pragma("unroll") for (int r = 0; r < 4; ++r) {                         \
        pe[r] = EXP2(__builtin_fmaf(S[2 * ko][r], sc, -mcur));                \
        po[r] = EXP2(__builtin_fmaf(S[2 * ko + 1][r], sc, -mcur));            \
      }                                                                       \
      const u32 aw = pk2(pe[0], pe[1]), bw2 = pk2(pe[2], pe[3]);              \
      const u32 cw = pk2(po[0], po[1]), dw = pk2(po[2], po[3]);               \
      const i32x2 s1_ =                                                       \
          __builtin_amdgcn_permlane32_swap((int)aw, (int)cw, false, false);   \
      const i32x2 s2_ =                                                       \
          __builtin_amdgcn_permlane32_swap((int)bw2, (int)dw, false, false);  \
      const u32x4 wv = {(u32)s1_[0], (u32)s2_[0], (u32)s1_[1], (u32)s2_[1]};  \
      const bf16x8 pf = __builtin_bit_cast(bf16x8, wv);                       \
      __builtin_amdgcn_s_setprio(1);                                          \
      _Pragma("unroll") for (int ni = 0; ni < 4; ++ni) {                      \
        const bf16x8 bv =                                                     \
            *(const bf16x8*)&Vs[B][(ko * 4 + ni) * 512 + lane * 8];           \
        AC[ni] = MFMA_16x16x32(pf, bv, AC[ni]);                               \
      }                                                                       \
      LS = MFMA_16x16x32(pf, ones, LS);                                       \
      __builtin_amdgcn_s_setprio(0);                                          \
    }                                                                         \
  } while (0)

#define ITER(KT, B)                                                           \
  do {                                                                        \
    if ((KT) < qt) { /* issue V(kt+1) a full tile ahead */                    \
      _Pragma("unroll") for (int i = 0; i < 4; ++i)                           \
          gload16(vp + i * 4096, &Vs[(B) ^ 1][(i * 4 + w) * 512 + lane * 8]); \
      vp += 16384;                                                            \
    }                                                                         \
    _Pragma("unroll") for (int mi = 0; mi < 2; ++mi) {                        \
      f32x4 s[8] = {};                                                        \
      __builtin_amdgcn_s_setprio(1);                                          \
      _Pragma("unroll") for (int dc = 0; dc < 2; ++dc) {                      \
        const bf16x8 qf = bq[mi][dc];                                         \
        _Pragma("unroll") for (int ki = 0; ki < 8; ++ki) {                    \
          const bf16x8 ak =                                                   \
              *(const bf16x8*)&Ks[(dc * 8 + ki) * 512 + lane * 8];            \
          s[ki] = MFMA_16x16x32(ak, qf, s[ki]);                               \
        }                                                                     \
      }                                                                       \
      __builtin_amdgcn_s_setprio(0);                                          \
      if ((KT) == qt) {                                                       \
        const int qq = w * 32 + mi * 16 + cc;                                 \
        _Pragma("unroll") for (int ki = 0; ki < 8; ++ki) {                    \
          const int kb_ = ki * 16 + 4 * g;                                    \
          _Pragma("unroll") for (int r = 0; r < 4; ++r)                       \
            if (kb_ + r > qq) s[ki][r] = -1e30f;                              \
        }                                                                     \
      }                                                                       \
      if (mi == 0) SMPV(s, m_run[0], lsum[0], acc[0], B);                     \
      else SMPV(s, m_run[1], lsum[1], acc[1], B);                             \
    }                                                                         \
    if ((KT) < qt) {                                                          \
      __builtin_amdgcn_s_barrier(); /* all waves done reading Ks */           \
      _Pragma("unroll") for (int i = 0; i < 4; ++i)                           \
          *(u32x4*)&Ks[(i * 4 + w) * 512 + lane * 8] = kreg[i];               \
      if ((KT) + 1 < qt) {                                                    \
        _Pragma("unroll") for (int i = 0; i < 4; ++i)                         \
            kreg[i] = *(const u32x4*)(kp + i * 4096);                         \
        kp += 16384;                                                          \
        asm volatile("s_waitcnt vmcnt(4) lgkmcnt(0)" ::: "memory");           \
      } else {                                                                \
        asm volatile("s_waitcnt vmcnt(0) lgkmcnt(0)" ::: "memory");           \
      }                                                                       \
      __builtin_amdgcn_s_barrier();                                           \
    }                                                                         \
  } while (0)

  int kt = 0;
  while (kt + 1 <= qt) {
    ITER(kt, 0);
    ITER(kt + 1, 1);
    kt += 2;
  }
  if (kt <= qt) ITER(kt, 0);

#undef ITER
#undef SMPV

  // epilogue: O/l -> gemm2-A-tiled bf16 (row = b*2048+tq, k-dim = h*64+d)
  const int b = bh >> 4, h = bh & 15;
#pragma unroll
  for (int mi = 0; mi < 2; ++mi) {
    f32x4 inv;
#pragma unroll
    for (int r = 0; r < 4; ++r) inv[r] = 1.f / lsum[mi][r];
#pragma unroll
    for (int ni = 0; ni < 4; ++ni) {
      const int d = h * 64 + ni * 16 + cc;
      const int kbA = d >> 5, koA = (d >> 3) & 3, eA = d & 7;
#pragma unroll
      for (int r = 0; r < 4; ++r) {
        const int tq = q0 + mi * 16 + 4 * g + r;
        const int row = b * 2048 + tq;
        const int R = row >> 7, rr = row & 127;
        const int fA = ((rr >> 6) << 2) + ((rr >> 4) & 3);
        Ob[(((size_t)R * 32 + kbA) * 8 + fA) * 512 + ((koA << 4) + (rr & 15)) * 8 + eA] =
            f2bf(acc[mi][ni][r] * inv[r]);
      }
    }
  }
}

// ---------- launch ----------

extern "C" void kernel_launch(void* const* d_in, const int* in_sizes, int n_in,
                              void* d_out, int out_size, void* d_ws, size_t ws_size,
                              hipStream_t stream) {
  const float* x     = (const float*)d_in[0];
  const float* w_qkv = (const float*)d_in[1];
  const float* b_qkv = (const float*)d_in[2];
  const float* w_out = (const float*)d_in[3];
  const float* b_out = (const float*)d_in[4];
  float* out = (float*)d_out;
  char* ws = (char*)d_ws;

  u16* xb    = (u16*)(ws + 0);          // 8192*1024 bf16 tiled = 16 MB (then attn out)
  u16* wqkvT = (u16*)(ws + 16777216);   // 3072*1024 bf16 tiled = 6 MB
  u16* woutT = (u16*)(ws + 23068672);   // 1024*1024 bf16 tiled = 2 MB
  u16* qbuf  = (u16*)(ws + 25165824);   // 64*16*16*512 bf16 = 16 MB (flash-tiled)
  u16* kbuf  = (u16*)(ws + 41943040);   // 16 MB (flash-tiled)
  u16* vbuf  = (u16*)(ws + 58720256);   // 16 MB (flash-tiled, sigma in kk)

  cvt_to_bf16<<<4096, 256, 0, stream>>>(x, xb, 8388608);
  transpose_cvt<<<dim3(48, 16), 256, 0, stream>>>(w_qkv, wqkvT, 1024, 3072);
  transpose_cvt<<<dim3(16, 16), 256, 0, stream>>>(w_out, woutT, 1024, 1024);
  gemm_bt<0><<<24 * 64, 256, 0, stream>>>(xb, wqkvT, 1024, b_qkv,
                                          qbuf, kbuf, vbuf, nullptr, 3072, 24);
  flash_attn<<<1024, 256, 0, stream>>>(qbuf, kbuf, vbuf, xb);
  gemm_bt<1><<<8 * 64, 256, 0, stream>>>(xb, woutT, 1024, b_out,
                                         nullptr, nullptr, nullptr, out, 1024, 8);
}

// Round 14
// 156.499 us; speedup vs baseline: 1.2890x; 1.2890x over previous
//
#include <hip/hip_runtime.h>

typedef unsigned short u16;
typedef unsigned u32;
typedef float f32x4 __attribute__((ext_vector_type(4)));
typedef __bf16 bf16x8 __attribute__((ext_vector_type(8)));
typedef __bf16 bf16x2 __attribute__((ext_vector_type(2)));
typedef u32 u32x4 __attribute__((ext_vector_type(4)));
typedef u16 u16x4 __attribute__((ext_vector_type(4)));
typedef int i32x2 __attribute__((ext_vector_type(2)));

#define MFMA_16x16x32(a, b, c) __builtin_amdgcn_mfma_f32_16x16x32_bf16((a), (b), (c), 0, 0, 0)

#if __has_builtin(__builtin_amdgcn_exp2f)
#define EXP2(x) __builtin_amdgcn_exp2f(x)
#else
#define EXP2(x) exp2f(x)
#endif

// ---------- helpers ----------

__device__ __forceinline__ u16 f2bf(float f) {
  unsigned u = __builtin_bit_cast(unsigned, f);
  unsigned r = ((u >> 16) & 1u) + 0x7FFFu;  // round-to-nearest-even
  return (u16)((u + r) >> 16);
}

__device__ __forceinline__ u32 pk2(float x, float y) {  // lo=x, hi=y as bf16
  bf16x2 v = {(__bf16)x, (__bf16)y};
  return __builtin_bit_cast(u32, v);
}

// async global->LDS, 16B per lane. LDS dest must be wave-uniform base + lane*16.
__device__ __forceinline__ void gload16(const void* g, void* l) {
  __builtin_amdgcn_global_load_lds(
      (const __attribute__((address_space(1))) void*)g,
      (__attribute__((address_space(3))) void*)l, 16, 0, 0);
}

// ===== GEMM operand tiling (K=1024, consumed as 128-row x 32-k tiles) =====
// frag f (0..7) of tile (R,kb): rows (f>>2)*64+(f&3)*16+(l&15), k (l>>4)*8+e.
// u16 offset(row,k) = ((R*32+kb)*8 + f)*512 + ((k>>3)&3)*128 + (row&15)*8 + (k&7)
//   R=row>>7, rr=row&127, f=(rr>>6)*4+((rr>>4)&3), kb=k>>5.
// Readers then stage with gload16 at (frag base + lane*16) -- fully coalesced.

// ---------- conversion kernels ----------

// x [8192][1024] fp32 -> xb tiled bf16. One thread = one 8-elem slot.
__global__ void cvt_to_bf16(const float* __restrict__ in, u16* __restrict__ out, int n) {
  const int s = blockIdx.x * 256 + threadIdx.x;  // slot index
  if (s * 8 >= n) return;
  const int l = s & 63, f = (s >> 6) & 7, kb = (s >> 9) & 31, R = s >> 14;
  const int rr = ((f >> 2) << 6) + ((f & 3) << 4) + (l & 15);
  const int row = (R << 7) + rr;
  const int k = (kb << 5) + ((l >> 4) << 3);
  const float* src = in + (size_t)row * 1024 + k;
  const f32x4 a = *(const f32x4*)src;
  const f32x4 b = *(const f32x4*)(src + 4);
  u16x4 u0, u1;
#pragma unroll
  for (int j = 0; j < 4; ++j) { u0[j] = f2bf(a[j]); u1[j] = f2bf(b[j]); }
  *(u16x4*)(out + (size_t)s * 8) = u0;
  *(u16x4*)(out + (size_t)s * 8 + 4) = u1;
}

// w [rows=K][cols=N] fp32 -> tiled-by-N bf16 (out(n,k) = w[k][n]).
__global__ void transpose_cvt(const float* __restrict__ in, u16* __restrict__ out,
                              int rows, int cols) {
  __shared__ float t[64][65];
  const int rb = blockIdx.y * 64, cb = blockIdx.x * 64;  // rb: k-base, cb: n-base
  for (int i = threadIdx.x; i < 4096; i += 256) {
    const int r = i >> 6, c = i & 63;
    t[r][c] = in[(size_t)(rb + r) * cols + cb + c];
  }
  __syncthreads();
  for (int u = threadIdx.x; u < 512; u += 256) {
    const int c = u >> 3, k8 = u & 7;
    const int nrow = cb + c;
    const int kg = rb + k8 * 8;
    const int R = nrow >> 7, rr = nrow & 127;
    const int fB = ((rr >> 6) << 2) + ((rr >> 4) & 3);
    const int kb = kg >> 5, koct = (kg >> 3) & 3;
    u16* dst = out + (((size_t)R * 32 + kb) * 8 + fB) * 512 + ((koct << 4) + (rr & 15)) * 8;
    u16x4 u0, u1;
#pragma unroll
    for (int j = 0; j < 4; ++j) {
      u0[j] = f2bf(t[k8 * 8 + j][c]);
      u1[j] = f2bf(t[k8 * 8 + 4 + j][c]);
    }
    *(u16x4*)dst = u0;
    *(u16x4*)(dst + 4) = u1;
  }
}

// ---------- GEMM: C = A * Bt^T + bias (A, Bt both DRAM-fragment-tiled) ----------
// 128x128 tile, BK=32, 2-phase static double-buffer (32 KB LDS), identity frag
// slots (conflict-free b128, zero per-iter addr VALU), coalesced 1KB gloads,
// XCD-swizzled block id.
// EPI=0: scatter to flash-tiled q/k/v buffers (bf16, +bias; V sigma-permuted)
// EPI=1: fp32 out[M][N] + bias (row-major)
template <int EPI>
__global__ __launch_bounds__(256, 4) void gemm_bt(
    const u16* __restrict__ A, const u16* __restrict__ Bt, int K,
    const float* __restrict__ bias,
    u16* __restrict__ oq, u16* __restrict__ ok, u16* __restrict__ ov,
    float* __restrict__ of, int N, int nbx) {
  __shared__ __align__(16) u16 As[2][4096];
  __shared__ __align__(16) u16 Bs[2][4096];
  const int tid = threadIdx.x;
  const int lane = tid & 63, w = tid >> 6;
  const int g = lane >> 4, cc = lane & 15;
  const int wr = w >> 1, wc = w & 1;

  // XCD-aware swizzle (grid is a multiple of 8 -> bijective)
  const int cpx = gridDim.x >> 3;
  const int bid = ((int)blockIdx.x & 7) * cpx + ((int)blockIdx.x >> 3);
  const int bx = bid % nbx, by = bid / nbx;

  // tiled sources: frag stride 512, 32-k tile stride 4096 (u16)
  const u16* pa = A + ((size_t)by * 256 + w) * 512 + lane * 8;
  const u16* pb = Bt + ((size_t)bx * 256 + w) * 512 + lane * 8;

  f32x4 acc[4][4] = {};

#define STG(S, T)                                              \
  do {                                                         \
    const size_t o_ = (size_t)(T) * 4096;                      \
    gload16(pa + o_, &As[S][w * 512 + lane * 8]);              \
    gload16(pa + o_ + 2048, &As[S][(w + 4) * 512 + lane * 8]); \
    gload16(pb + o_, &Bs[S][w * 512 + lane * 8]);              \
    gload16(pb + o_ + 2048, &Bs[S][(w + 4) * 512 + lane * 8]); \
  } while (0)

#define CMP(S, DOSTG, T)                                                 \
  do {                                                                   \
    bf16x8 af[4], bf[4];                                                 \
    _Pragma("unroll") for (int mi = 0; mi < 4; ++mi)                     \
        af[mi] = *(const bf16x8*)&As[S][(wr * 4 + mi) * 512 + lane * 8]; \
    _Pragma("unroll") for (int ni = 0; ni < 4; ++ni)                     \
        bf[ni] = *(const bf16x8*)&Bs[S][(wc * 4 + ni) * 512 + lane * 8]; \
    if (DOSTG) STG(S ^ 1, T);                                            \
    __builtin_amdgcn_s_setprio(1);                                       \
    _Pragma("unroll") for (int mi = 0; mi < 4; ++mi)                     \
      _Pragma("unroll") for (int ni = 0; ni < 4; ++ni)                   \
          acc[mi][ni] = MFMA_16x16x32(af[mi], bf[ni], acc[mi][ni]);      \
    __builtin_amdgcn_s_setprio(0);                                       \
  } while (0)

  STG(0, 0);
  __syncthreads();

  const int np = (K >> 5) >> 1;  // pairs of 32-k tiles (16 for K=1024)
  for (int p = 0; p < np - 1; ++p) {
    CMP(0, true, 2 * p + 1);
    __syncthreads();
    CMP(1, true, 2 * p + 2);
    __syncthreads();
  }
  CMP(0, true, 2 * np - 1);
  __syncthreads();
  CMP(1, false, 0);

#undef STG
#undef CMP

  // epilogue: D layout col=lane&15, row=(lane>>4)*4+r
  const int m00 = by * 128 + wr * 64 + 4 * g;
  const int n00 = bx * 128 + wc * 64;
#pragma unroll
  for (int ni = 0; ni < 4; ++ni) {
    const int n = n00 + ni * 16 + cc;
    const float bn = bias[n];
    if constexpr (EPI == 0) {
      const int which = n >> 10;  // 0=q 1=k 2=v (wave-uniform)
      const int d = n & 1023;
      const int h = d >> 6, dh = d & 63;
      const int dcf = dh >> 5, gf = (dh >> 3) & 3, e = dh & 7;  // q/k frag coords
      const int niv = dh >> 4, ccv = dh & 15;                   // v frag coords
#pragma unroll
      for (int mi = 0; mi < 4; ++mi) {
        const int mb = m00 + mi * 16;
        const int b = mb >> 11, t0b = mb & 2047;
        const int bh2 = b * 16 + h;
        const int kt = t0b >> 7, tr = t0b & 127;  // tr%4==0; r adds to low bits
        if (which == 2) {
          const int kk0 = (tr & ~12) | ((tr & 4) << 1) | ((tr & 8) >> 1);
          const int ko = kk0 >> 5, gv = (kk0 >> 3) & 3, ev = kk0 & 7;  // ev%4==0
          u16x4 pk;
#pragma unroll
          for (int r = 0; r < 4; ++r) pk[r] = f2bf(acc[mi][ni][r] + bn);
          *(u16x4*)&ov[(((size_t)bh2 * 16 + kt) * 16 + ko * 4 + niv) * 512 +
                       ((gv << 4) + ccv) * 8 + ev] = pk;
        } else if (which == 1) {
          const int ki = tr >> 4;
          u16* dst = ok + (((size_t)bh2 * 16 + kt) * 16 + dcf * 8 + ki) * 512 +
                     ((gf << 4) + (tr & 15)) * 8 + e;
#pragma unroll
          for (int r = 0; r < 4; ++r) dst[r * 8] = f2bf(acc[mi][ni][r] + bn);
        } else {
          const int wf = tr >> 5, mif = (tr >> 4) & 1;
          u16* dst = oq + (((size_t)bh2 * 16 + kt) * 16 + wf * 4 + mif * 2 + dcf) * 512 +
                     ((gf << 4) + (tr & 15)) * 8 + e;
#pragma unroll
          for (int r = 0; r < 4; ++r) dst[r * 8] = f2bf(acc[mi][ni][r] + bn);
        }
      }
    } else {
#pragma unroll
      for (int mi = 0; mi < 4; ++mi) {
        const int m = m00 + mi * 16;
#pragma unroll
        for (int r = 0; r < 4; ++r) of[(size_t)(m + r) * N + n] = acc[mi][ni][r] + bn;
      }
    }
  }
}

// ---------- causal flash attention ----------
// Swapped QK^T; stats 2 scalars/lane; PV A-frag via 2x permlane32_swap (sigma
// baked into V buffer). T14 async-STAGE: next K/V tile loaded to regs during
// compute, ds_write'd at the next barrier. launch_bounds(256,3): the unified
// VGPR+AGPR live set (~136 regs incl. 32 staging regs) must fit the cap.
// Row-max as balanced tree (v_max3-fusable). l computed by MFMA against ones.
// Work order: pure longest-first (LPT) -- robust to undefined block->CU maps
// at the measured 2-3 blocks/CU residency. Output in gemm2's A-tiled layout.
__global__ __launch_bounds__(256, 3) void flash_attn(
    const u16* __restrict__ Qb, const u16* __restrict__ Kb,
    const u16* __restrict__ Vt, u16* __restrict__ Ob) {
  __shared__ __align__(16) u16 Ks[8192];  // 16 frags x 64 lanes x 8
  __shared__ __align__(16) u16 Vs[8192];

  const int bid = blockIdx.x;
  const int qt = 15 - (bid >> 6);  // longest-first (LPT) ordering
  const int bh = bid & 63;
  const int tid = threadIdx.x;
  const int lane = tid & 63, w = tid >> 6;
  const int g = lane >> 4, cc = lane & 15;
  const int q0 = qt * 128 + w * 32;

  // Q tiled [bh][qt:16][frag:16][512], frag = w*4+mi*2+dc
  bf16x8 bq[2][2];
  {
    const u16* qp = Qb + (((size_t)bh * 16 + qt) * 16 + w * 4) * 512 + lane * 8;
#pragma unroll
    for (int mi = 0; mi < 2; ++mi)
#pragma unroll
      for (int dc = 0; dc < 2; ++dc)
        bq[mi][dc] = *(const bf16x8*)(qp + (mi * 2 + dc) * 512);
  }

  // K/V tiled [bh][kt:16][frag:16][512]; wave w owns frags i*4+w
  const char* kp = (const char*)Kb + (size_t)bh * 262144 + w * 1024 + lane * 16;
  const char* vp = (const char*)Vt + (size_t)bh * 262144 + w * 1024 + lane * 16;
  u16* kl[4];
  u16* vl[4];
#pragma unroll
  for (int i = 0; i < 4; ++i) {
    kl[i] = &Ks[(i * 4 + w) * 512 + lane * 8];
    vl[i] = &Vs[(i * 4 + w) * 512 + lane * 8];
  }
  const u16* krd = &Ks[lane * 8];
  const u16* vrd = &Vs[lane * 8];

  // ones B-fragment for the MFMA row-sum (1.0 bf16 = 0x3F80)
  const u32x4 ones_u = {0x3F803F80u, 0x3F803F80u, 0x3F803F80u, 0x3F803F80u};
  const bf16x8 ones = __builtin_bit_cast(bf16x8, ones_u);

  f32x4 acc[2][4] = {};
  f32x4 lsum[2] = {};               // D-layout: lsum[mi][r] = l for q-row 4g+r
  float m_run[2] = {-1e30f, -1e30f};
  const float sc = 0.18033688011112042f;  // (1/8) * log2(e)

  // prologue: tile 0 -> regs
  u32x4 kreg[4], vreg[4];
#pragma unroll
  for (int i = 0; i < 4; ++i) {
    kreg[i] = *(const u32x4*)(kp + i * 4096);
    vreg[i] = *(const u32x4*)(vp + i * 4096);
  }
  kp += 16384;
  vp += 16384;

  for (int kt = 0; kt <= qt; ++kt) {
    __syncthreads();  // previous tile's LDS reads done
#pragma unroll
    for (int i = 0; i < 4; ++i) {
      *(u32x4*)kl[i] = kreg[i];
      *(u32x4*)vl[i] = vreg[i];
    }
    if (kt < qt) {  // prefetch next tile into regs; lands during compute
#pragma unroll
      for (int i = 0; i < 4; ++i) {
        kreg[i] = *(const u32x4*)(kp + i * 4096);
        vreg[i] = *(const u32x4*)(vp + i * 4096);
      }
      kp += 16384;
      vp += 16384;
    }
    __syncthreads();  // ds_writes visible

#pragma unroll
    for (int mi = 0; mi < 2; ++mi) {
      // S^T[k][q]: s[ki], k = kt*128 + ki*16 + 4g + r, q = q0 + mi*16 + cc
      f32x4 s[8] = {};
      __builtin_amdgcn_s_setprio(1);
#pragma unroll
      for (int dc = 0; dc < 2; ++dc) {
        const bf16x8 qf = bq[mi][dc];
#pragma unroll
        for (int ki = 0; ki < 8; ++ki) {
          const bf16x8 ak = *(const bf16x8*)(krd + (dc * 8 + ki) * 512);
          s[ki] = MFMA_16x16x32(ak, qf, s[ki]);
        }
      }
      __builtin_amdgcn_s_setprio(0);

      if (kt == qt) {  // causal mask on diagonal tile
        const int qq = w * 32 + mi * 16 + cc;
#pragma unroll
        for (int ki = 0; ki < 8; ++ki) {
          const int kb_ = ki * 16 + 4 * g;
#pragma unroll
          for (int r = 0; r < 4; ++r)
            if (kb_ + r > qq) s[ki][r] = -1e30f;
        }
      }

      // row max: balanced tree (depth 5, max3-fusable), then 2 cross-lane steps
      float t4[8];
#pragma unroll
      for (int ki = 0; ki < 8; ++ki)
        t4[ki] = fmaxf(fmaxf(s[ki][0], s[ki][1]), fmaxf(s[ki][2], s[ki][3]));
      float mx = fmaxf(fmaxf(fmaxf(t4[0], t4[1]), fmaxf(t4[2], t4[3])),
                       fmaxf(fmaxf(t4[4], t4[5]), fmaxf(t4[6], t4[7])));
      mx = fmaxf(mx, __shfl_xor(mx, 16));
      mx = fmaxf(mx, __shfl_xor(mx, 32));
      const float pm = mx * sc;

      // defer-max (T13): only rescale when max grew by > 8 (P bounded by 2^8)
      if (!__all(pm - m_run[mi] <= 8.f)) {
        const float mn = fmaxf(m_run[mi], pm);
        const float sf = EXP2(m_run[mi] - mn);
        m_run[mi] = mn;
        float sfr[4];
#pragma unroll
        for (int r = 0; r < 4; ++r) sfr[r] = __shfl(sf, (lane & 48) + 4 * g + r);
#pragma unroll
        for (int r = 0; r < 4; ++r) lsum[mi][r] *= sfr[r];
#pragma unroll
        for (int ni = 0; ni < 4; ++ni)
#pragma unroll
          for (int r = 0; r < 4; ++r) acc[mi][ni][r] *= sfr[r];
      }
      const float mcur = m_run[mi];

#pragma unroll
      for (int ko = 0; ko < 4; ++ko) {
        // P for k-block 32ko: even ki (k=+4g+r) and odd ki (k=+16+4g+r)
        f32x4 pe, po;
#pragma unroll
        for (int r = 0; r < 4; ++r) {
          pe[r] = EXP2(__builtin_fmaf(s[2 * ko][r], sc, -mcur));
          po[r] = EXP2(__builtin_fmaf(s[2 * ko + 1][r], sc, -mcur));
        }
        const u32 aw = pk2(pe[0], pe[1]), bw2 = pk2(pe[2], pe[3]);
        const u32 cw = pk2(po[0], po[1]), dw = pk2(po[2], po[3]);
#if __has_builtin(__builtin_amdgcn_permlane32_swap)
        const i32x2 s1 = __builtin_amdgcn_permlane32_swap((int)aw, (int)cw, false, false);
        const i32x2 s2 = __builtin_amdgcn_permlane32_swap((int)bw2, (int)dw, false, false);
        const u32x4 wv = {(u32)s1[0], (u32)s2[0], (u32)s1[1], (u32)s2[1]};
#else
        const bool lo2 = (g < 2);
        const u32 r_ac = __shfl_xor(lo2 ? cw : aw, 32);
        const u32 r_bd = __shfl_xor(lo2 ? dw : bw2, 32);
        const u32x4 wv = {lo2 ? aw : r_ac, lo2 ? bw2 : r_bd,
                          lo2 ? r_ac : cw, lo2 ? r_bd : dw};
#endif
        const bf16x8 pf = __builtin_bit_cast(bf16x8, wv);
        __builtin_amdgcn_s_setprio(1);
#pragma unroll
        for (int ni = 0; ni < 4; ++ni) {
          const bf16x8 bv = *(const bf16x8*)(vrd + (ko * 4 + ni) * 512);
          acc[mi][ni] = MFMA_16x16x32(pf, bv, acc[mi][ni]);
        }
        lsum[mi] = MFMA_16x16x32(pf, ones, lsum[mi]);  // row-sum on matrix pipe
        __builtin_amdgcn_s_setprio(0);
      }
    }
  }

  // epilogue: O/l -> gemm2-A-tiled bf16 (row = b*2048+tq, k-dim = h*64+d)
  const int b = bh >> 4, h = bh & 15;
#pragma unroll
  for (int mi = 0; mi < 2; ++mi) {
    f32x4 inv;
#pragma unroll
    for (int r = 0; r < 4; ++r) inv[r] = 1.f / lsum[mi][r];
#pragma unroll
    for (int ni = 0; ni < 4; ++ni) {
      const int d = h * 64 + ni * 16 + cc;
      const int kbA = d >> 5, koA = (d >> 3) & 3, eA = d & 7;
#pragma unroll
      for (int r = 0; r < 4; ++r) {
        const int tq = q0 + mi * 16 + 4 * g + r;
        const int row = b * 2048 + tq;
        const int R = row >> 7, rr = row & 127;
        const int fA = ((rr >> 6) << 2) + ((rr >> 4) & 3);
        Ob[(((size_t)R * 32 + kbA) * 8 + fA) * 512 + ((koA << 4) + (rr & 15)) * 8 + eA] =
            f2bf(acc[mi][ni][r] * inv[r]);
      }
    }
  }
}

// ---------- launch ----------

extern "C" void kernel_launch(void* const* d_in, const int* in_sizes, int n_in,
                              void* d_out, int out_size, void* d_ws, size_t ws_size,
                              hipStream_t stream) {
  const float* x     = (const float*)d_in[0];
  const float* w_qkv = (const float*)d_in[1];
  const float* b_qkv = (const float*)d_in[2];
  const float* w_out = (const float*)d_in[3];
  const float* b_out = (const float*)d_in[4];
  float* out = (float*)d_out;
  char* ws = (char*)d_ws;

  u16* xb    = (u16*)(ws + 0);          // 8192*1024 bf16 tiled = 16 MB (then attn out)
  u16* wqkvT = (u16*)(ws + 16777216);   // 3072*1024 bf16 tiled = 6 MB
  u16* woutT = (u16*)(ws + 23068672);   // 1024*1024 bf16 tiled = 2 MB
  u16* qbuf  = (u16*)(ws + 25165824);   // 64*16*16*512 bf16 = 16 MB (flash-tiled)
  u16* kbuf  = (u16*)(ws + 41943040);   // 16 MB (flash-tiled)
  u16* vbuf  = (u16*)(ws + 58720256);   // 16 MB (flash-tiled, sigma in kk)

  cvt_to_bf16<<<4096, 256, 0, stream>>>(x, xb, 8388608);
  transpose_cvt<<<dim3(48, 16), 256, 0, stream>>>(w_qkv, wqkvT, 1024, 3072);
  transpose_cvt<<<dim3(16, 16), 256, 0, stream>>>(w_out, woutT, 1024, 1024);
  gemm_bt<0><<<24 * 64, 256, 0, stream>>>(xb, wqkvT, 1024, b_qkv,
                                          qbuf, kbuf, vbuf, nullptr, 3072, 24);
  flash_attn<<<1024, 256, 0, stream>>>(qbuf, kbuf, vbuf, xb);
  gemm_bt<1><<<8 * 64, 256, 0, stream>>>(xb, woutT, 1024, b_out,
                                         nullptr, nullptr, nullptr, out, 1024, 8);
}

// Round 15
// 155.335 us; speedup vs baseline: 1.2987x; 1.0075x over previous
//
#include <hip/hip_runtime.h>

typedef unsigned short u16;
typedef unsigned u32;
typedef float f32x4 __attribute__((ext_vector_type(4)));
typedef __bf16 bf16x8 __attribute__((ext_vector_type(8)));
typedef __bf16 bf16x2 __attribute__((ext_vector_type(2)));
typedef u32 u32x4 __attribute__((ext_vector_type(4)));
typedef u16 u16x4 __attribute__((ext_vector_type(4)));
typedef int i32x2 __attribute__((ext_vector_type(2)));

#define MFMA_16x16x32(a, b, c) __builtin_amdgcn_mfma_f32_16x16x32_bf16((a), (b), (c), 0, 0, 0)

#if __has_builtin(__builtin_amdgcn_exp2f)
#define EXP2(x) __builtin_amdgcn_exp2f(x)
#else
#define EXP2(x) exp2f(x)
#endif

// ---------- helpers ----------

__device__ __forceinline__ u16 f2bf(float f) {
  unsigned u = __builtin_bit_cast(unsigned, f);
  unsigned r = ((u >> 16) & 1u) + 0x7FFFu;  // round-to-nearest-even
  return (u16)((u + r) >> 16);
}

__device__ __forceinline__ u32 pk2(float x, float y) {  // lo=x, hi=y as bf16
  bf16x2 v = {(__bf16)x, (__bf16)y};
  return __builtin_bit_cast(u32, v);
}

__device__ __forceinline__ u16x4 pk4(f32x4 v) {
  u16x4 o;
#pragma unroll
  for (int j = 0; j < 4; ++j) o[j] = f2bf(v[j]);
  return o;
}

// 4x4 transpose across a lane quad (lt = lane&3). In: v[r] = A[r][lt].
// Out: v[j] = A[lt][j]. Two xor-butterfly stages; shfl_xor(1/2) lower to
// quad-perm DPP (VALU-cheap, no LDS).
__device__ __forceinline__ void quad_transpose(f32x4& v, int lt) {
  {
    float a0 = (lt & 1) ? v[0] : v[1];
    float a1 = (lt & 1) ? v[2] : v[3];
    float b0 = __shfl_xor(a0, 1);
    float b1 = __shfl_xor(a1, 1);
    if (lt & 1) { v[0] = b0; v[2] = b1; } else { v[1] = b0; v[3] = b1; }
  }
  {
    float a0 = (lt & 2) ? v[0] : v[2];
    float a1 = (lt & 2) ? v[1] : v[3];
    float b0 = __shfl_xor(a0, 2);
    float b1 = __shfl_xor(a1, 2);
    if (lt & 2) { v[0] = b0; v[1] = b1; } else { v[2] = b0; v[3] = b1; }
  }
}

// async global->LDS, 16B per lane. LDS dest must be wave-uniform base + lane*16.
__device__ __forceinline__ void gload16(const void* g, void* l) {
  __builtin_amdgcn_global_load_lds(
      (const __attribute__((address_space(1))) void*)g,
      (__attribute__((address_space(3))) void*)l, 16, 0, 0);
}

// ===== GEMM operand tiling (K=1024, consumed as 128-row x 32-k tiles) =====
// frag f (0..7) of tile (R,kb): rows (f>>2)*64+(f&3)*16+(l&15), k (l>>4)*8+e.
// u16 offset(row,k) = ((R*32+kb)*8 + f)*512 + ((k>>3)&3)*128 + (row&15)*8 + (k&7)
//   R=row>>7, rr=row&127, f=(rr>>6)*4+((rr>>4)&3), kb=k>>5.
// Readers then stage with gload16 at (frag base + lane*16) -- fully coalesced.

// ---------- conversion kernels ----------

// x [8192][1024] fp32 -> xb tiled bf16. One thread = one 8-elem slot.
__global__ void cvt_to_bf16(const float* __restrict__ in, u16* __restrict__ out, int n) {
  const int s = blockIdx.x * 256 + threadIdx.x;  // slot index
  if (s * 8 >= n) return;
  const int l = s & 63, f = (s >> 6) & 7, kb = (s >> 9) & 31, R = s >> 14;
  const int rr = ((f >> 2) << 6) + ((f & 3) << 4) + (l & 15);
  const int row = (R << 7) + rr;
  const int k = (kb << 5) + ((l >> 4) << 3);
  const float* src = in + (size_t)row * 1024 + k;
  const f32x4 a = *(const f32x4*)src;
  const f32x4 b = *(const f32x4*)(src + 4);
  u16x4 u0, u1;
#pragma unroll
  for (int j = 0; j < 4; ++j) { u0[j] = f2bf(a[j]); u1[j] = f2bf(b[j]); }
  *(u16x4*)(out + (size_t)s * 8) = u0;
  *(u16x4*)(out + (size_t)s * 8 + 4) = u1;
}

// w [rows=K][cols=N] fp32 -> tiled-by-N bf16 (out(n,k) = w[k][n]).
__global__ void transpose_cvt(const float* __restrict__ in, u16* __restrict__ out,
                              int rows, int cols) {
  __shared__ float t[64][65];
  const int rb = blockIdx.y * 64, cb = blockIdx.x * 64;  // rb: k-base, cb: n-base
  for (int i = threadIdx.x; i < 4096; i += 256) {
    const int r = i >> 6, c = i & 63;
    t[r][c] = in[(size_t)(rb + r) * cols + cb + c];
  }
  __syncthreads();
  for (int u = threadIdx.x; u < 512; u += 256) {
    const int c = u >> 3, k8 = u & 7;
    const int nrow = cb + c;
    const int kg = rb + k8 * 8;
    const int R = nrow >> 7, rr = nrow & 127;
    const int fB = ((rr >> 6) << 2) + ((rr >> 4) & 3);
    const int kb = kg >> 5, koct = (kg >> 3) & 3;
    u16* dst = out + (((size_t)R * 32 + kb) * 8 + fB) * 512 + ((koct << 4) + (rr & 15)) * 8;
    u16x4 u0, u1;
#pragma unroll
    for (int j = 0; j < 4; ++j) {
      u0[j] = f2bf(t[k8 * 8 + j][c]);
      u1[j] = f2bf(t[k8 * 8 + 4 + j][c]);
    }
    *(u16x4*)dst = u0;
    *(u16x4*)(dst + 4) = u1;
  }
}

// ---------- GEMM: C = A * Bt^T + bias (A, Bt both DRAM-fragment-tiled) ----------
// 128x128 tile, BK=32, 2-phase static double-buffer (32 KB LDS), identity frag
// slots (conflict-free b128, zero per-iter addr VALU), coalesced 1KB gloads,
// XCD-swizzled block id. Epilogue uses quad_transpose so q/k (EPI=0) and fp32
// out (EPI=1) are written with vector stores (u16x4 / f32x4) instead of 64
// scalar 2B/4B stores per thread.
// EPI=0: scatter to flash-tiled q/k/v buffers (bf16, +bias; V sigma-permuted)
// EPI=1: fp32 out[M][N] + bias (row-major)
template <int EPI>
__global__ __launch_bounds__(256, 4) void gemm_bt(
    const u16* __restrict__ A, const u16* __restrict__ Bt, int K,
    const float* __restrict__ bias,
    u16* __restrict__ oq, u16* __restrict__ ok, u16* __restrict__ ov,
    float* __restrict__ of, int N, int nbx) {
  __shared__ __align__(16) u16 As[2][4096];
  __shared__ __align__(16) u16 Bs[2][4096];
  const int tid = threadIdx.x;
  const int lane = tid & 63, w = tid >> 6;
  const int g = lane >> 4, cc = lane & 15;
  const int wr = w >> 1, wc = w & 1;

  // XCD-aware swizzle (grid is a multiple of 8 -> bijective)
  const int cpx = gridDim.x >> 3;
  const int bid = ((int)blockIdx.x & 7) * cpx + ((int)blockIdx.x >> 3);
  const int bx = bid % nbx, by = bid / nbx;

  // tiled sources: frag stride 512, 32-k tile stride 4096 (u16)
  const u16* pa = A + ((size_t)by * 256 + w) * 512 + lane * 8;
  const u16* pb = Bt + ((size_t)bx * 256 + w) * 512 + lane * 8;

  f32x4 acc[4][4] = {};

#define STG(S, T)                                              \
  do {                                                         \
    const size_t o_ = (size_t)(T) * 4096;                      \
    gload16(pa + o_, &As[S][w * 512 + lane * 8]);              \
    gload16(pa + o_ + 2048, &As[S][(w + 4) * 512 + lane * 8]); \
    gload16(pb + o_, &Bs[S][w * 512 + lane * 8]);              \
    gload16(pb + o_ + 2048, &Bs[S][(w + 4) * 512 + lane * 8]); \
  } while (0)

#define CMP(S, DOSTG, T)                                                 \
  do {                                                                   \
    bf16x8 af[4], bf[4];                                                 \
    _Pragma("unroll") for (int mi = 0; mi < 4; ++mi)                     \
        af[mi] = *(const bf16x8*)&As[S][(wr * 4 + mi) * 512 + lane * 8]; \
    _Pragma("unroll") for (int ni = 0; ni < 4; ++ni)                     \
        bf[ni] = *(const bf16x8*)&Bs[S][(wc * 4 + ni) * 512 + lane * 8]; \
    if (DOSTG) STG(S ^ 1, T);                                            \
    __builtin_amdgcn_s_setprio(1);                                       \
    _Pragma("unroll") for (int mi = 0; mi < 4; ++mi)                     \
      _Pragma("unroll") for (int ni = 0; ni < 4; ++ni)                   \
          acc[mi][ni] = MFMA_16x16x32(af[mi], bf[ni], acc[mi][ni]);      \
    __builtin_amdgcn_s_setprio(0);                                       \
  } while (0)

  STG(0, 0);
  __syncthreads();

  const int np = (K >> 5) >> 1;  // pairs of 32-k tiles (16 for K=1024)
  for (int p = 0; p < np - 1; ++p) {
    CMP(0, true, 2 * p + 1);
    __syncthreads();
    CMP(1, true, 2 * p + 2);
    __syncthreads();
  }
  CMP(0, true, 2 * np - 1);
  __syncthreads();
  CMP(1, false, 0);

#undef STG
#undef CMP

  // epilogue: D layout col=lane&15, row=(lane>>4)*4+r; m00 includes +4g
  const int m00 = by * 128 + wr * 64 + 4 * g;
  const int n00 = bx * 128 + wc * 64;
  const int lt = cc & 3, cc0 = cc & 12;

  if constexpr (EPI == 0) {
    const int which = (n00 + cc) >> 10;  // wave-uniform (64-col span, 64-aligned)
    if (which == 2) {
      // V path: already r-vectorized (kk = sigma(t) varies with r) -- unchanged
#pragma unroll
      for (int ni = 0; ni < 4; ++ni) {
        const int n = n00 + ni * 16 + cc;
        const float bn = bias[n];
        const int d = n & 1023;
        const int h = d >> 6, dh = d & 63;
        const int niv = dh >> 4, ccv = dh & 15;
#pragma unroll
        for (int mi = 0; mi < 4; ++mi) {
          const int mb = m00 + mi * 16;
          const int b = mb >> 11, t0b = mb & 2047;
          const int bh2 = b * 16 + h;
          const int kt = t0b >> 7, tr = t0b & 127;
          const int kk0 = (tr & ~12) | ((tr & 4) << 1) | ((tr & 8) >> 1);  // sigma
          const int ko = kk0 >> 5, gv = (kk0 >> 3) & 3, ev = kk0 & 7;
          u16x4 pk;
#pragma unroll
          for (int r = 0; r < 4; ++r) pk[r] = f2bf(acc[mi][ni][r] + bn);
          *(u16x4*)&ov[(((size_t)bh2 * 16 + kt) * 16 + ko * 4 + niv) * 512 +
                       ((gv << 4) + ccv) * 8 + ev] = pk;
        }
      }
    } else {
      // q/k path: quad-transpose -> one u16x4 store per (mi,ni)
#pragma unroll
      for (int ni = 0; ni < 4; ++ni) {
        const float bn = bias[n00 + ni * 16 + cc];  // per-col, add pre-transpose
        const int nb = n00 + ni * 16 + cc0;         // 4-col span, never crosses octet
        const int d = nb & 1023;
        const int h = d >> 6;
        const int dcf = (d >> 5) & 1, gf = (d >> 3) & 3, e0 = d & 7;
#pragma unroll
        for (int mi = 0; mi < 4; ++mi) {
          f32x4 vals;
#pragma unroll
          for (int r = 0; r < 4; ++r) vals[r] = acc[mi][ni][r] + bn;
          quad_transpose(vals, lt);
          const int row = m00 + mi * 16 + lt;  // this thread's single row
          const int b = row >> 11, t0b = row & 2047;
          const int bh2 = b * 16 + h;
          const int kt = t0b >> 7, trf = t0b & 127;
          u16* dst;
          if (which == 1) {
            const int ki = trf >> 4;
            dst = ok + (((size_t)bh2 * 16 + kt) * 16 + dcf * 8 + ki) * 512 +
                  ((gf << 4) + (trf & 15)) * 8 + e0;
          } else {
            const int wf = trf >> 5, mif = (trf >> 4) & 1;
            dst = oq + (((size_t)bh2 * 16 + kt) * 16 + wf * 4 + mif * 2 + dcf) * 512 +
                  ((gf << 4) + (trf & 15)) * 8 + e0;
          }
          *(u16x4*)dst = pk4(vals);
        }
      }
    }
  } else {
    // fp32 row-major out: quad-transpose -> one f32x4 store per (mi,ni)
#pragma unroll
    for (int ni = 0; ni < 4; ++ni) {
      const float bn = bias[n00 + ni * 16 + cc];
#pragma unroll
      for (int mi = 0; mi < 4; ++mi) {
        f32x4 vals;
#pragma unroll
        for (int r = 0; r < 4; ++r) vals[r] = acc[mi][ni][r] + bn;
        quad_transpose(vals, lt);
        const int row = m00 + mi * 16 + lt;
        *(f32x4*)&of[(size_t)row * N + n00 + ni * 16 + cc0] = vals;
      }
    }
  }
}

// ---------- causal flash attention ----------
// Swapped QK^T; stats 2 scalars/lane; PV A-frag via 2x permlane32_swap (sigma
// baked into V buffer). T14 async-STAGE: next K/V tile loaded to regs during
// compute, ds_write'd at the next barrier. launch_bounds(256,3): the unified
// VGPR+AGPR live set (~136 regs incl. 32 staging regs) must fit the cap.
// Row-max as balanced tree. l via MFMA against ones. LPT work order.
// Epilogue quad-transposed -> u16x4 stores. Output in gemm2's A-tiled layout.
__global__ __launch_bounds__(256, 3) void flash_attn(
    const u16* __restrict__ Qb, const u16* __restrict__ Kb,
    const u16* __restrict__ Vt, u16* __restrict__ Ob) {
  __shared__ __align__(16) u16 Ks[8192];  // 16 frags x 64 lanes x 8
  __shared__ __align__(16) u16 Vs[8192];

  const int bid = blockIdx.x;
  const int qt = 15 - (bid >> 6);  // longest-first (LPT) ordering
  const int bh = bid & 63;
  const int tid = threadIdx.x;
  const int lane = tid & 63, w = tid >> 6;
  const int g = lane >> 4, cc = lane & 15;
  const int q0 = qt * 128 + w * 32;

  // Q tiled [bh][qt:16][frag:16][512], frag = w*4+mi*2+dc
  bf16x8 bq[2][2];
  {
    const u16* qp = Qb + (((size_t)bh * 16 + qt) * 16 + w * 4) * 512 + lane * 8;
#pragma unroll
    for (int mi = 0; mi < 2; ++mi)
#pragma unroll
      for (int dc = 0; dc < 2; ++dc)
        bq[mi][dc] = *(const bf16x8*)(qp + (mi * 2 + dc) * 512);
  }

  // K/V tiled [bh][kt:16][frag:16][512]; wave w owns frags i*4+w
  const char* kp = (const char*)Kb + (size_t)bh * 262144 + w * 1024 + lane * 16;
  const char* vp = (const char*)Vt + (size_t)bh * 262144 + w * 1024 + lane * 16;
  u16* kl[4];
  u16* vl[4];
#pragma unroll
  for (int i = 0; i < 4; ++i) {
    kl[i] = &Ks[(i * 4 + w) * 512 + lane * 8];
    vl[i] = &Vs[(i * 4 + w) * 512 + lane * 8];
  }
  const u16* krd = &Ks[lane * 8];
  const u16* vrd = &Vs[lane * 8];

  // ones B-fragment for the MFMA row-sum (1.0 bf16 = 0x3F80)
  const u32x4 ones_u = {0x3F803F80u, 0x3F803F80u, 0x3F803F80u, 0x3F803F80u};
  const bf16x8 ones = __builtin_bit_cast(bf16x8, ones_u);

  f32x4 acc[2][4] = {};
  f32x4 lsum[2] = {};               // D-layout: lsum[mi][r] = l for q-row 4g+r
  float m_run[2] = {-1e30f, -1e30f};
  const float sc = 0.18033688011112042f;  // (1/8) * log2(e)

  // prologue: tile 0 -> regs
  u32x4 kreg[4], vreg[4];
#pragma unroll
  for (int i = 0; i < 4; ++i) {
    kreg[i] = *(const u32x4*)(kp + i * 4096);
    vreg[i] = *(const u32x4*)(vp + i * 4096);
  }
  kp += 16384;
  vp += 16384;

  for (int kt = 0; kt <= qt; ++kt) {
    __syncthreads();  // previous tile's LDS reads done
#pragma unroll
    for (int i = 0; i < 4; ++i) {
      *(u32x4*)kl[i] = kreg[i];
      *(u32x4*)vl[i] = vreg[i];
    }
    if (kt < qt) {  // prefetch next tile into regs; lands during compute
#pragma unroll
      for (int i = 0; i < 4; ++i) {
        kreg[i] = *(const u32x4*)(kp + i * 4096);
        vreg[i] = *(const u32x4*)(vp + i * 4096);
      }
      kp += 16384;
      vp += 16384;
    }
    __syncthreads();  // ds_writes visible

#pragma unroll
    for (int mi = 0; mi < 2; ++mi) {
      // S^T[k][q]: s[ki], k = kt*128 + ki*16 + 4g + r, q = q0 + mi*16 + cc
      f32x4 s[8] = {};
      __builtin_amdgcn_s_setprio(1);
#pragma unroll
      for (int dc = 0; dc < 2; ++dc) {
        const bf16x8 qf = bq[mi][dc];
#pragma unroll
        for (int ki = 0; ki < 8; ++ki) {
          const bf16x8 ak = *(const bf16x8*)(krd + (dc * 8 + ki) * 512);
          s[ki] = MFMA_16x16x32(ak, qf, s[ki]);
        }
      }
      __builtin_amdgcn_s_setprio(0);

      if (kt == qt) {  // causal mask on diagonal tile
        const int qq = w * 32 + mi * 16 + cc;
#pragma unroll
        for (int ki = 0; ki < 8; ++ki) {
          const int kb_ = ki * 16 + 4 * g;
#pragma unroll
          for (int r = 0; r < 4; ++r)
            if (kb_ + r > qq) s[ki][r] = -1e30f;
        }
      }

      // row max: balanced tree (depth 5, max3-fusable), then 2 cross-lane steps
      float t4[8];
#pragma unroll
      for (int ki = 0; ki < 8; ++ki)
        t4[ki] = fmaxf(fmaxf(s[ki][0], s[ki][1]), fmaxf(s[ki][2], s[ki][3]));
      float mx = fmaxf(fmaxf(fmaxf(t4[0], t4[1]), fmaxf(t4[2], t4[3])),
                       fmaxf(fmaxf(t4[4], t4[5]), fmaxf(t4[6], t4[7])));
      mx = fmaxf(mx, __shfl_xor(mx, 16));
      mx = fmaxf(mx, __shfl_xor(mx, 32));
      const float pm = mx * sc;

      // defer-max (T13): only rescale when max grew by > 8 (P bounded by 2^8)
      if (!__all(pm - m_run[mi] <= 8.f)) {
        const float mn = fmaxf(m_run[mi], pm);
        const float sf = EXP2(m_run[mi] - mn);
        m_run[mi] = mn;
        float sfr[4];
#pragma unroll
        for (int r = 0; r < 4; ++r) sfr[r] = __shfl(sf, (lane & 48) + 4 * g + r);
#pragma unroll
        for (int r = 0; r < 4; ++r) lsum[mi][r] *= sfr[r];
#pragma unroll
        for (int ni = 0; ni < 4; ++ni)
#pragma unroll
          for (int r = 0; r < 4; ++r) acc[mi][ni][r] *= sfr[r];
      }
      const float mcur = m_run[mi];

#pragma unroll
      for (int ko = 0; ko < 4; ++ko) {
        // P for k-block 32ko: even ki (k=+4g+r) and odd ki (k=+16+4g+r)
        f32x4 pe, po;
#pragma unroll
        for (int r = 0; r < 4; ++r) {
          pe[r] = EXP2(__builtin_fmaf(s[2 * ko][r], sc, -mcur));
          po[r] = EXP2(__builtin_fmaf(s[2 * ko + 1][r], sc, -mcur));
        }
        const u32 aw = pk2(pe[0], pe[1]), bw2 = pk2(pe[2], pe[3]);
        const u32 cw = pk2(po[0], po[1]), dw = pk2(po[2], po[3]);
#if __has_builtin(__builtin_amdgcn_permlane32_swap)
        const i32x2 s1 = __builtin_amdgcn_permlane32_swap((int)aw, (int)cw, false, false);
        const i32x2 s2 = __builtin_amdgcn_permlane32_swap((int)bw2, (int)dw, false, false);
        const u32x4 wv = {(u32)s1[0], (u32)s2[0], (u32)s1[1], (u32)s2[1]};
#else
        const bool lo2 = (g < 2);
        const u32 r_ac = __shfl_xor(lo2 ? cw : aw, 32);
        const u32 r_bd = __shfl_xor(lo2 ? dw : bw2, 32);
        const u32x4 wv = {lo2 ? aw : r_ac, lo2 ? bw2 : r_bd,
                          lo2 ? r_ac : cw, lo2 ? r_bd : dw};
#endif
        const bf16x8 pf = __builtin_bit_cast(bf16x8, wv);
        __builtin_amdgcn_s_setprio(1);
#pragma unroll
        for (int ni = 0; ni < 4; ++ni) {
          const bf16x8 bv = *(const bf16x8*)(vrd + (ko * 4 + ni) * 512);
          acc[mi][ni] = MFMA_16x16x32(pf, bv, acc[mi][ni]);
        }
        lsum[mi] = MFMA_16x16x32(pf, ones, lsum[mi]);  // row-sum on matrix pipe
        __builtin_amdgcn_s_setprio(0);
      }
    }
  }

  // epilogue: O/l -> gemm2-A-tiled bf16; normalize pre-transpose (inv is
  // per-row in D-layout), then quad-transpose -> one u16x4 store per (mi,ni)
  const int b = bh >> 4, h = bh & 15;
  const int lt = cc & 3, cc0 = cc & 12;
#pragma unroll
  for (int mi = 0; mi < 2; ++mi) {
    f32x4 inv;
#pragma unroll
    for (int r = 0; r < 4; ++r) inv[r] = 1.f / lsum[mi][r];
    const int tq = q0 + mi * 16 + 4 * g + lt;  // this thread's single row
    const int row = b * 2048 + tq;
    const int R = row >> 7, rr = row & 127;
    const int fA = ((rr >> 6) << 2) + ((rr >> 4) & 3);
#pragma unroll
    for (int ni = 0; ni < 4; ++ni) {
      f32x4 vals;
#pragma unroll
      for (int r = 0; r < 4; ++r) vals[r] = acc[mi][ni][r] * inv[r];
      quad_transpose(vals, lt);
      const int d0 = h * 64 + ni * 16 + cc0;  // 4 consecutive k-dim elems
      const int kbA = d0 >> 5, koA = (d0 >> 3) & 3, eA0 = d0 & 7;
      *(u16x4*)&Ob[(((size_t)R * 32 + kbA) * 8 + fA) * 512 +
                   ((koA << 4) + (rr & 15)) * 8 + eA0] = pk4(vals);
    }
  }
}

// ---------- launch ----------

extern "C" void kernel_launch(void* const* d_in, const int* in_sizes, int n_in,
                              void* d_out, int out_size, void* d_ws, size_t ws_size,
                              hipStream_t stream) {
  const float* x     = (const float*)d_in[0];
  const float* w_qkv = (const float*)d_in[1];
  const float* b_qkv = (const float*)d_in[2];
  const float* w_out = (const float*)d_in[3];
  const float* b_out = (const float*)d_in[4];
  float* out = (float*)d_out;
  char* ws = (char*)d_ws;

  u16* xb    = (u16*)(ws + 0);          // 8192*1024 bf16 tiled = 16 MB (then attn out)
  u16* wqkvT = (u16*)(ws + 16777216);   // 3072*1024 bf16 tiled = 6 MB
  u16* woutT = (u16*)(ws + 23068672);   // 1024*1024 bf16 tiled = 2 MB
  u16* qbuf  = (u16*)(ws + 25165824);   // 64*16*16*512 bf16 = 16 MB (flash-tiled)
  u16* kbuf  = (u16*)(ws + 41943040);   // 16 MB (flash-tiled)
  u16* vbuf  = (u16*)(ws + 58720256);   // 16 MB (flash-tiled, sigma in kk)

  cvt_to_bf16<<<4096, 256, 0, stream>>>(x, xb, 8388608);
  transpose_cvt<<<dim3(48, 16), 256, 0, stream>>>(w_qkv, wqkvT, 1024, 3072);
  transpose_cvt<<<dim3(16, 16), 256, 0, stream>>>(w_out, woutT, 1024, 1024);
  gemm_bt<0><<<24 * 64, 256, 0, stream>>>(xb, wqkvT, 1024, b_qkv,
                                          qbuf, kbuf, vbuf, nullptr, 3072, 24);
  flash_attn<<<1024, 256, 0, stream>>>(qbuf, kbuf, vbuf, xb);
  gemm_bt<1><<<8 * 64, 256, 0, stream>>>(xb, woutT, 1024, b_out,
                                         nullptr, nullptr, nullptr, out, 1024, 8);
}